// Round 1
// 10271.387 us; speedup vs baseline: 1.2979x; 1.2979x over previous
//
#include <hip/hip_runtime.h>

typedef __bf16 bf16x8 __attribute__((ext_vector_type(8)));
typedef float  f32x4  __attribute__((ext_vector_type(4)));

#define Z0S 520   // z0 row (elems): [h_row 0:256 | h_col 256:512 | x 512:520]
#define Z1S 1032  // z1 row: [h_row | h_col | out0_row 512:768 | out0_col 768:1024] + 8 pad
#define W0_ELEMS (1536 * 520)
#define W1_ELEMS (1536 * 1024)

__device__ __forceinline__ unsigned short f2bf(float f) {
    unsigned int u = __builtin_bit_cast(unsigned int, f);
    u += 0x7fffu + ((u >> 16) & 1u);   // RNE
    return (unsigned short)(u >> 16);
}
// clamped, NaN-proof activations
__device__ __forceinline__ float sigm(float x) {
    x = fminf(30.f, fmaxf(-30.f, x));
    return __fdividef(1.0f, 1.0f + __expf(-x));
}
__device__ __forceinline__ float ftanh(float x) {
    x = fminf(15.f, fmaxf(-15.f, x));
    float e = __expf(2.0f * x);
    return 1.0f - __fdividef(2.0f, e + 1.0f);
}
__device__ __forceinline__ bf16x8 zero8() {
    bf16x8 v;
#pragma unroll
    for (int i = 0; i < 8; ++i) v[i] = (__bf16)0.0f;
    return v;
}

// fp32 -> bf16 weight conversion into d_ws (runs every call; ws re-poisoned each launch)
__global__ void convert_w(const float* __restrict__ W0f, const float* __restrict__ W1f,
                          unsigned short* __restrict__ Wb) {
    const int total = W0_ELEMS + W1_ELEMS;
    for (int i = blockIdx.x * blockDim.x + threadIdx.x; i < total; i += gridDim.x * blockDim.x) {
        const float v = (i < W0_ELEMS) ? W0f[i] : W1f[i - W0_ELEMS];
        Wb[i] = f2bf(v);
    }
}

// One workgroup per batch element b. 1024 threads = 16 waves (4/SIMD); wave w
// owns gate columns [16w, 16w+16) of each 256-wide gate group -> gating is
// lane-local. Restructure rationale (this round): acc[2][6] = 48 VGPRs (was
// acc[2][6][2] = 96), freeing registers for in-flight weight loads, and 4
// waves/SIMD (was 2) doubles latency hiding on the L2/L3 weight stream.
// MFMA 16x16x32 bf16: A[m=lane&15][k=quad*8+j], B[k=quad*8+j][n=lane&15],
// D: col=lane&15, row=quad*4+reg (HW-verified, guide m89/m91).
// fp32 recurrent state in registers; h_col roll via fp32 LDS buffer.
__global__ __launch_bounds__(1024, 4) void witran_fused(
    const float* __restrict__ inp,             // (64,32,32,8) fp32
    const unsigned short* __restrict__ W0,     // (1536,520)  bf16 (converted)
    const unsigned short* __restrict__ W1,     // (1536,1024) bf16 (converted)
    const float* __restrict__ Bias,            // (2,1536)    fp32
    float* __restrict__ out)                   // fp32 outputs
{
    const int b    = blockIdx.x;
    const int tid  = threadIdx.x;
    const int wave = tid >> 6;                 // 0..15
    const int lane = tid & 63;
    const int quad = lane >> 4;
    const int l16  = lane & 15;
    const int jj   = wave * 16 + l16;          // gate column within 256-group

    __shared__ __align__(16) unsigned short z0[32 * Z0S];
    __shared__ __align__(16) unsigned short z1[32 * Z1S];
    __shared__ float rollbuf[32 * 256];

    for (int idx = tid; idx < 32 * Z0S; idx += 1024) z0[idx] = 0;
    for (int idx = tid; idx < 32 * Z1S; idx += 1024) z1[idx] = 0;
    __syncthreads();
    if (tid < 256) {                           // stage x for t=0
        const int m = tid >> 3, i = tid & 7;
        const int c = 0 - m;
        float v = 0.f;
        if (c >= 0 && c < 32) v = inp[((b * 32 + m) * 32 + c) * 8 + i];
        z0[m * Z0S + 512 + i] = f2bf(v);
    }

    float biasr[2][6];
#pragma unroll
    for (int L = 0; L < 2; ++L)
#pragma unroll
        for (int G = 0; G < 6; ++G)
            biasr[L][G] = Bias[L * 1536 + G * 256 + jj];

    // fp32 state: [layer][mt][p] <-> row m = mt*16+quad*4+p, col jj
    float hrreg[2][2][4];
    float hcreg[2][2][4];
#pragma unroll
    for (int L = 0; L < 2; ++L)
#pragma unroll
        for (int mt = 0; mt < 2; ++mt)
#pragma unroll
            for (int p = 0; p < 4; ++p) { hrreg[L][mt][p] = 0.f; hcreg[L][mt][p] = 0.f; }

    __syncthreads();

    const size_t OUT1 = 66060288u;           // hidden_row_all (64,2,32,256)
    const size_t OUT2 = OUT1 + 1048576u;     // hidden_col_all (64,2,32,256)

    float hcn[2][4];

    for (int t = 0; t < 63; ++t) {
        // =================== phase A: GEMM0 (reads z0) + gating0 ===================
        f32x4 acc[2][6];
#pragma unroll
        for (int mt = 0; mt < 2; ++mt)
#pragma unroll
            for (int G = 0; G < 6; ++G)
                acc[mt][G] = (f32x4){0.f, 0.f, 0.f, 0.f};

#pragma unroll 4
        for (int ks = 0; ks < 16; ++ks) {
            const int k0 = ks * 32 + quad * 8;
            bf16x8 a0 = *(const bf16x8*)&z0[(l16)      * Z0S + k0];
            bf16x8 a1 = *(const bf16x8*)&z0[(16 + l16) * Z0S + k0];
#pragma unroll
            for (int G = 0; G < 6; ++G) {
                bf16x8 bf = *(const bf16x8*)&W0[(size_t)(G * 256 + jj) * 520 + k0];
                acc[0][G] = __builtin_amdgcn_mfma_f32_16x16x32_bf16(a0, bf, acc[0][G], 0, 0, 0);
                acc[1][G] = __builtin_amdgcn_mfma_f32_16x16x32_bf16(a1, bf, acc[1][G], 0, 0, 0);
            }
        }
        {   // partial k-step: x cols 512..519 live on quad 0; quads 1-3 contribute zero
            const bf16x8 z8 = zero8();
            bf16x8 a0 = z8, a1 = z8;
            if (quad == 0) {
                a0 = *(const bf16x8*)&z0[(l16)      * Z0S + 512];
                a1 = *(const bf16x8*)&z0[(16 + l16) * Z0S + 512];
            }
#pragma unroll
            for (int G = 0; G < 6; ++G) {
                bf16x8 bf = z8;
                if (quad == 0) bf = *(const bf16x8*)&W0[(size_t)(G * 256 + jj) * 520 + 512];
                acc[0][G] = __builtin_amdgcn_mfma_f32_16x16x32_bf16(a0, bf, acc[0][G], 0, 0, 0);
                acc[1][G] = __builtin_amdgcn_mfma_f32_16x16x32_bf16(a1, bf, acc[1][G], 0, 0, 0);
            }
        }

#pragma unroll
        for (int mt = 0; mt < 2; ++mt)
#pragma unroll
            for (int p = 0; p < 4; ++p) {
                const int m = mt * 16 + quad * 4 + p;
                float g0 = acc[mt][0][p], g1 = acc[mt][1][p], g2 = acc[mt][2][p];
                float g3 = acc[mt][3][p], g4 = acc[mt][4][p], g5 = acc[mt][5][p];
                if ((t < 32) && (m <= t)) {
                    g0 += biasr[0][0]; g1 += biasr[0][1]; g2 += biasr[0][2];
                    g3 += biasr[0][3]; g4 += biasr[0][4]; g5 += biasr[0][5];
                }
                const float u_r = sigm(g0), o_r = sigm(g1), u_c = sigm(g2), o_c = sigm(g3);
                const float i_r = ftanh(g4), i_c = ftanh(g5);
                const float hrp = hrreg[0][mt][p];
                const float hcp = hcreg[0][mt][p];
                hrreg[0][mt][p] = ftanh((1.f - u_r) * hrp + u_r * i_r) * o_r;
                hcn[mt][p]      = ftanh((1.f - u_c) * hcp + u_c * i_c) * o_c;
            }
        __syncthreads();   // B1: all z0 reads of step t done

        // =================== phase B: layer-0 epilogue ===================
#pragma unroll
        for (int mt = 0; mt < 2; ++mt)
#pragma unroll
            for (int p = 0; p < 4; ++p) {
                const int m  = mt * 16 + quad * 4 + p;
                const float hrf = hrreg[0][mt][p];
                const float hcf = hcn[mt][p];
                const unsigned short hrb = f2bf(hrf), hcb = f2bf(hcf);
                z0[m * Z0S + jj] = hrb;
                z0[((m + 1) & 31) * Z0S + 256 + jj] = hcb;   // rolled h_col (bf16)
                z1[m * Z1S + 512 + jj] = hrb;                // layer-1 x input
                z1[m * Z1S + 768 + jj] = hcb;
                rollbuf[m * 256 + jj] = hcf;                 // fp32 pre-roll
                if (t >= 31) {
                    if (m == t - 31) out[OUT1 + ((size_t)(b * 2 + 0) * 32 + (t - 31)) * 256 + jj] = hrf;
                    if (m == 31)     out[OUT2 + ((size_t)(b * 2 + 0) * 32 + (t - 31)) * 256 + jj] = hcf;
                }
            }
        if (tid < 256 && t + 1 < 63) {     // stage x for t+1
            const int m = tid >> 3, i = tid & 7;
            const int c = t + 1 - m;
            float v = 0.f;
            if (c >= 0 && c < 32) v = inp[((b * 32 + m) * 32 + c) * 8 + i];
            z0[m * Z0S + 512 + i] = f2bf(v);
        }
        __syncthreads();   // B2: z1-x / rollbuf / z0 next-state published

        // fp32 roll readback, layer 0: new h_col[m] = computed[(m-1) mod 32]
#pragma unroll
        for (int mt = 0; mt < 2; ++mt)
#pragma unroll
            for (int p = 0; p < 4; ++p) {
                const int m = mt * 16 + quad * 4 + p;
                hcreg[0][mt][p] = rollbuf[((m + 31) & 31) * 256 + jj];
            }

        // =================== phase C: GEMM1 (reads z1) + gating1 ===================
#pragma unroll
        for (int mt = 0; mt < 2; ++mt)
#pragma unroll
            for (int G = 0; G < 6; ++G)
                acc[mt][G] = (f32x4){0.f, 0.f, 0.f, 0.f};

#pragma unroll 4
        for (int ks = 0; ks < 32; ++ks) {
            const int k0 = ks * 32 + quad * 8;
            bf16x8 a0 = *(const bf16x8*)&z1[(l16)      * Z1S + k0];
            bf16x8 a1 = *(const bf16x8*)&z1[(16 + l16) * Z1S + k0];
#pragma unroll
            for (int G = 0; G < 6; ++G) {
                bf16x8 bf = *(const bf16x8*)&W1[(size_t)(G * 256 + jj) * 1024 + k0];
                acc[0][G] = __builtin_amdgcn_mfma_f32_16x16x32_bf16(a0, bf, acc[0][G], 0, 0, 0);
                acc[1][G] = __builtin_amdgcn_mfma_f32_16x16x32_bf16(a1, bf, acc[1][G], 0, 0, 0);
            }
        }

#pragma unroll
        for (int mt = 0; mt < 2; ++mt)
#pragma unroll
            for (int p = 0; p < 4; ++p) {
                const int m = mt * 16 + quad * 4 + p;
                float g0 = acc[mt][0][p], g1 = acc[mt][1][p], g2 = acc[mt][2][p];
                float g3 = acc[mt][3][p], g4 = acc[mt][4][p], g5 = acc[mt][5][p];
                if ((t < 32) && (m <= t)) {
                    g0 += biasr[1][0]; g1 += biasr[1][1]; g2 += biasr[1][2];
                    g3 += biasr[1][3]; g4 += biasr[1][4]; g5 += biasr[1][5];
                }
                const float u_r = sigm(g0), o_r = sigm(g1), u_c = sigm(g2), o_c = sigm(g3);
                const float i_r = ftanh(g4), i_c = ftanh(g5);
                const float hrp = hrreg[1][mt][p];
                const float hcp = hcreg[1][mt][p];
                hrreg[1][mt][p] = ftanh((1.f - u_r) * hrp + u_r * i_r) * o_r;
                hcn[mt][p]      = ftanh((1.f - u_c) * hcp + u_c * i_c) * o_c;
            }
        __syncthreads();   // B3: all z1 / rollbuf reads of step t done

        // =================== phase D: layer-1 epilogue ===================
#pragma unroll
        for (int mt = 0; mt < 2; ++mt)
#pragma unroll
            for (int p = 0; p < 4; ++p) {
                const int m  = mt * 16 + quad * 4 + p;
                const float hrf = hrreg[1][mt][p];
                const float hcf = hcn[mt][p];
                const unsigned short hrb = f2bf(hrf), hcb = f2bf(hcf);
                z1[m * Z1S + jj] = hrb;
                z1[((m + 1) & 31) * Z1S + 256 + jj] = hcb;
                rollbuf[m * 256 + jj] = hcf;
                const size_t row = (size_t)(m * 64 + b);
                out[(row * 63 + t) * 512 + jj]       = hrf;   // output_all (fp32)
                out[(row * 63 + t) * 512 + 256 + jj] = hcf;
                if (t >= 31) {
                    if (m == t - 31) out[OUT1 + ((size_t)(b * 2 + 1) * 32 + (t - 31)) * 256 + jj] = hrf;
                    if (m == 31)     out[OUT2 + ((size_t)(b * 2 + 1) * 32 + (t - 31)) * 256 + jj] = hcf;
                }
            }
        __syncthreads();   // B4: z1 next-state + rollbuf published

#pragma unroll
        for (int mt = 0; mt < 2; ++mt)
#pragma unroll
            for (int p = 0; p < 4; ++p) {
                const int m = mt * 16 + quad * 4 + p;
                hcreg[1][mt][p] = rollbuf[((m + 31) & 31) * 256 + jj];
            }
    }
}

extern "C" void kernel_launch(void* const* d_in, const int* in_sizes, int n_in,
                              void* d_out, int out_size, void* d_ws, size_t ws_size,
                              hipStream_t stream) {
    (void)in_sizes; (void)n_in; (void)out_size; (void)ws_size;
    const float* inp   = (const float*)d_in[0];   // (64,32,32,8) fp32
    const float* W0f   = (const float*)d_in[1];   // (1536,520)  fp32
    const float* W1f   = (const float*)d_in[2];   // (1,1536,1024) fp32
    const float* Biasf = (const float*)d_in[3];   // (2,1536) fp32
    float* out = (float*)d_out;                   // fp32 output (reference dtype)

    unsigned short* Wb = (unsigned short*)d_ws;   // 4.74 MB: [W0 bf16 | W1 bf16]
    convert_w<<<dim3(512), dim3(256), 0, stream>>>(W0f, W1f, Wb);
    witran_fused<<<dim3(64), dim3(1024), 0, stream>>>(inp, Wb, Wb + W0_ELEMS, Biasf, out);
}